// Round 2
// baseline (9744.921 us; speedup 1.0000x reference)
//
#include <hip/hip_runtime.h>
#include <cstdint>
#include <cstddef>

#define T_OBS_C 64
#define T_UNOBS_C 32
#define BATCH_C 4096
#define HID_C 256

typedef short v8s __attribute__((ext_vector_type(8)));
typedef float v4f __attribute__((ext_vector_type(4)));
typedef unsigned short u16x8 __attribute__((ext_vector_type(8)));

__device__ __forceinline__ float bf2f(unsigned short u) {
  union { unsigned int i; float f; } v; v.i = ((unsigned int)u) << 16; return v.f;
}
__device__ __forceinline__ unsigned short f2bf(float f) {
  union { float f; unsigned int i; } v; v.f = f;
  unsigned int r = (v.i + 0x7FFFu + ((v.i >> 16) & 1u)) >> 16;
  return (unsigned short)r;
}

// ---------------------------------------------------------------------------
// prep:
//   Wc = wi @ stem_w2  (fp32, so gx_t = stem1_t @ Wc.T + bc_obs)  -> hi/lo bf16
//   wi, wh -> hi/lo bf16 splits
//   bc_obs[n] = sum_j wi[n][j]*b2[j] + bi[n]   (fp32)
// ---------------------------------------------------------------------------
__global__ void prep_kernel(const float* __restrict__ wi,
                            const float* __restrict__ w2,
                            const float* __restrict__ b2,
                            const float* __restrict__ bi,
                            unsigned short* __restrict__ wi_hi,
                            unsigned short* __restrict__ wi_lo,
                            const float* __restrict__ wh,
                            unsigned short* __restrict__ wh_hi,
                            unsigned short* __restrict__ wh_lo,
                            unsigned short* __restrict__ wc_hi,
                            unsigned short* __restrict__ wc_lo,
                            float* __restrict__ bc_obs) {
  const int n = blockIdx.x;     // 0..767
  const int k = threadIdx.x;    // 0..255
  const int idx = n * 256 + k;

  float wv = wi[idx];
  unsigned short h1 = f2bf(wv);
  wi_hi[idx] = h1; wi_lo[idx] = f2bf(wv - bf2f(h1));

  float hv = wh[idx];
  unsigned short h2 = f2bf(hv);
  wh_hi[idx] = h2; wh_lo[idx] = f2bf(hv - bf2f(h2));

  float acc = 0.f;
  for (int j = 0; j < 256; ++j)
    acc += wi[n * 256 + j] * w2[j * 256 + k];
  unsigned short h3 = f2bf(acc);
  wc_hi[idx] = h3; wc_lo[idx] = f2bf(acc - bf2f(h3));

  if (k == 0) {
    float b = 0.f;
    for (int j = 0; j < 256; ++j) b += wi[n * 256 + j] * b2[j];
    bc_obs[n] = b + bi[n];
  }
}

// ---------------------------------------------------------------------------
// Persistent RNN kernel: 256 blocks x 512 threads. Block b owns batch rows
// [b*16, b*16+16) and ALL 768 gate columns -> blocks are fully independent
// across all 95 time steps (no grid sync needed). h lives in LDS (hi/lo bf16)
// for the whole kernel. Weights stream from L2 each step. head is fused.
// ---------------------------------------------------------------------------
__global__ __launch_bounds__(512, 2)
void rnn_persistent(const float* __restrict__ x_obs,
                    const float* __restrict__ t_obs,
                    const float* __restrict__ w1,
                    const float* __restrict__ b1,
                    const unsigned short* __restrict__ wi_hi,
                    const unsigned short* __restrict__ wi_lo,
                    const unsigned short* __restrict__ wh_hi,
                    const unsigned short* __restrict__ wh_lo,
                    const unsigned short* __restrict__ wc_hi,
                    const unsigned short* __restrict__ wc_lo,
                    const float* __restrict__ bc_obs,
                    const float* __restrict__ bi,
                    const float* __restrict__ bh,
                    const float* __restrict__ head_w,
                    const float* __restrict__ head_b,
                    float* __restrict__ out_x,
                    float* __restrict__ out_z) {
  // 16 rows x 256 cols, hi+lo, XOR-swizzled per 8-elem chunk: 4 x 8KB = 32KB
  __shared__ __align__(16) unsigned short lds_h_hi[4096];
  __shared__ __align__(16) unsigned short lds_h_lo[4096];
  __shared__ __align__(16) unsigned short lds_x_hi[4096];
  __shared__ __align__(16) unsigned short lds_x_lo[4096];

  const int tid  = threadIdx.x;
  const int m0   = blockIdx.x << 4;      // 16 batch rows per block
  const int wave = tid >> 6;             // 0..7
  const int lane = tid & 63;
  const int quad = lane >> 4;
  const int l16  = lane & 15;
  const int jw   = wave << 5;            // this wave's 32 h-cols

  // h0 = 0
  for (int i = tid; i < 4096; i += 512) { lds_h_hi[i] = 0; lds_h_lo[i] = 0; }

  // per-thread epilogue biases (jcol fixed for the whole kernel)
  float xb_o[2][3], xb_a[2][3], hb_[2][3];
  #pragma unroll
  for (int nf = 0; nf < 2; ++nf) {
    const int jc = jw + nf * 16 + l16;
    #pragma unroll
    for (int g = 0; g < 3; ++g) {
      xb_o[nf][g] = bc_obs[g * 256 + jc];
      xb_a[nf][g] = bi[g * 256 + jc];
      hb_[nf][g]  = bh[g * 256 + jc];
    }
  }

  // fused-head thread mapping: (row, d, k-slice)
  const int xr_row = tid >> 5;           // 0..15
  const int xr_d   = (tid >> 3) & 3;     // 0..3
  const int xr_ks  = tid & 7;            // 0..7  (32 k each)
  const float hb_d = head_b[xr_d];

  __syncthreads();

  // ---- one GRU step: GEMM (x-path s=0, h-path s=1) + gate epilogue into LDS h
  auto do_step = [&](const unsigned short* a0h, const unsigned short* a0l,
                     const unsigned short* bx_h, const unsigned short* bx_l,
                     int obsflag) {
    v4f acc[2][6];
    #pragma unroll
    for (int nf = 0; nf < 2; ++nf)
      #pragma unroll
      for (int q = 0; q < 6; ++q)
        acc[nf][q] = (v4f){0.f, 0.f, 0.f, 0.f};

    #pragma unroll
    for (int s = 0; s < 2; ++s) {
      const unsigned short* ah_p = s ? lds_h_hi : a0h;
      const unsigned short* al_p = s ? lds_h_lo : a0l;
      const unsigned short* bh_p = s ? wh_hi : bx_h;
      const unsigned short* bl_p = s ? wh_lo : bx_l;
      #pragma unroll
      for (int kc = 0; kc < 8; ++kc) {
        v8s bfh[3][2], bfl[3][2];
        #pragma unroll
        for (int g = 0; g < 3; ++g)
          #pragma unroll
          for (int nf = 0; nf < 2; ++nf) {
            const int bo = ((g * 256 + jw + nf * 16 + l16) << 8) + kc * 32 + quad * 8;
            bfh[g][nf] = *(const v8s*)(bh_p + bo);
            bfl[g][nf] = *(const v8s*)(bl_p + bo);
          }
        const int chunk = ((kc * 4 + quad) ^ (l16 & 7));
        const int aoff  = (l16 << 8) + (chunk << 3);
        const v8s ahi = *(const v8s*)(ah_p + aoff);
        const v8s alo = *(const v8s*)(al_p + aoff);
        #pragma unroll
        for (int g = 0; g < 3; ++g)
          #pragma unroll
          for (int nf = 0; nf < 2; ++nf) {
            acc[nf][s * 3 + g] = __builtin_amdgcn_mfma_f32_16x16x32_bf16(
                ahi, bfh[g][nf], acc[nf][s * 3 + g], 0, 0, 0);
            acc[nf][s * 3 + g] = __builtin_amdgcn_mfma_f32_16x16x32_bf16(
                alo, bfh[g][nf], acc[nf][s * 3 + g], 0, 0, 0);
            acc[nf][s * 3 + g] = __builtin_amdgcn_mfma_f32_16x16x32_bf16(
                ahi, bfl[g][nf], acc[nf][s * 3 + g], 0, 0, 0);
          }
      }
    }

    __syncthreads();  // all MFMA LDS reads done before h is overwritten

    #pragma unroll
    for (int nf = 0; nf < 2; ++nf) {
      const int jcol = jw + nf * 16 + l16;
      #pragma unroll
      for (int rg = 0; rg < 4; ++rg) {
        const int rl = quad * 4 + rg;   // local row 0..15
        const float xbr = obsflag ? xb_o[nf][0] : xb_a[nf][0];
        const float xbz = obsflag ? xb_o[nf][1] : xb_a[nf][1];
        const float xbn = obsflag ? xb_o[nf][2] : xb_a[nf][2];
        float gr = acc[nf][0][rg] + xbr + acc[nf][3][rg] + hb_[nf][0];
        float gz = acc[nf][1][rg] + xbz + acc[nf][4][rg] + hb_[nf][1];
        float nx = acc[nf][2][rg] + xbn;
        float nh = acc[nf][5][rg] + hb_[nf][2];
        float r = 1.f / (1.f + expf(-gr));
        float u = 1.f / (1.f + expf(-gz));
        float n = tanhf(nx + r * nh);
        const int hp = (rl << 8) + ((((jcol >> 3) ^ (rl & 7))) << 3) + (jcol & 7);
        float hold = bf2f(lds_h_hi[hp]) + bf2f(lds_h_lo[hp]);
        float hnew = (1.f - u) * n + u * hold;
        unsigned short hi = f2bf(hnew);
        lds_h_hi[hp] = hi;
        lds_h_lo[hp] = f2bf(hnew - bf2f(hi));
      }
    }
  };

  // ---- fused z + head output: out_z[zi] and out_x[zi] from LDS h
  auto emit = [&](int zi) {
    __syncthreads();  // epilogue h writes visible
    float accx = 0.f;
    #pragma unroll
    for (int c = 0; c < 4; ++c) {
      const int k8 = xr_ks * 4 + c;
      const int hp = (xr_row << 8) + ((k8 ^ (xr_row & 7)) << 3);
      const u16x8 vh = *(const u16x8*)(lds_h_hi + hp);
      const u16x8 vl = *(const u16x8*)(lds_h_lo + hp);
      float f[8];
      #pragma unroll
      for (int j = 0; j < 8; ++j) f[j] = bf2f(vh[j]) + bf2f(vl[j]);
      const float* wd = head_w + xr_d * 256 + k8 * 8;
      const float4 w0 = *(const float4*)(wd);
      const float4 w1v = *(const float4*)(wd + 4);
      accx += f[0] * w0.x + f[1] * w0.y + f[2] * w0.z + f[3] * w0.w;
      accx += f[4] * w1v.x + f[5] * w1v.y + f[6] * w1v.z + f[7] * w1v.w;
      if (xr_d == 0) {
        float* zp = out_z + ((size_t)zi << 20) + ((size_t)(m0 + xr_row) << 8) + k8 * 8;
        float4 o0 = {f[0], f[1], f[2], f[3]};
        float4 o1 = {f[4], f[5], f[6], f[7]};
        *(float4*)zp = o0;
        *(float4*)(zp + 4) = o1;
      }
    }
    accx += __shfl_xor(accx, 1);
    accx += __shfl_xor(accx, 2);
    accx += __shfl_xor(accx, 4);
    if (xr_ks == 0)
      out_x[(((size_t)zi << 12) + m0 + xr_row) * 4 + xr_d] = accx + hb_d;
  };

  // ================= observed phase: 64 steps =================
  #pragma unroll 1
  for (int t = 0; t < T_OBS_C; ++t) {
    // stem1 = leaky_relu(xt @ w1.T + b1), exact fp32, into lds_x (hi/lo)
    {
      const int row = tid >> 5;          // 0..15
      const int cg  = tid & 31;          // 8-col group
      const size_t xo = (size_t)t * BATCH_C + m0 + row;
      const float4 xv = *(const float4*)(x_obs + xo * 4);
      float td = 0.f;
      if (t > 0) td = t_obs[xo] - t_obs[xo - BATCH_C];
      const float* wr = w1 + cg * 40;    // 8 rows x 5, contiguous
      u16x8 hi8, lo8;
      #pragma unroll
      for (int j = 0; j < 8; ++j) {
        float pre = xv.x * wr[j * 5 + 0] + xv.y * wr[j * 5 + 1] +
                    xv.z * wr[j * 5 + 2] + xv.w * wr[j * 5 + 3] +
                    td * wr[j * 5 + 4] + b1[cg * 8 + j];
        float a = (pre > 0.f) ? pre : 0.01f * pre;   // leaky_relu slope 0.01
        unsigned short h = f2bf(a);
        hi8[j] = h;
        lo8[j] = f2bf(a - bf2f(h));
      }
      const int phys = (row << 8) + ((cg ^ (row & 7)) << 3);
      *(u16x8*)(lds_x_hi + phys) = hi8;
      *(u16x8*)(lds_x_lo + phys) = lo8;
    }
    __syncthreads();
    do_step(lds_x_hi, lds_x_lo, wc_hi, wc_lo, 1);
  }
  emit(0);  // z_last

  // ================= autoregressive phase: 31 steps =================
  #pragma unroll 1
  for (int i = 1; i < T_UNOBS_C; ++i) {
    __syncthreads();  // prior h writes / emit reads complete
    do_step(lds_h_hi, lds_h_lo, wi_hi, wi_lo, 0);
    emit(i);
  }
}

// ---------------------------------------------------------------------------
extern "C" void kernel_launch(void* const* d_in, const int* in_sizes, int n_in,
                              void* d_out, int out_size, void* d_ws, size_t ws_size,
                              hipStream_t stream) {
  const float* x_obs = (const float*)d_in[0];
  const float* t_obs = (const float*)d_in[1];
  // d_in[2] = t_unobs: only its length (32) matters
  const float* w1 = (const float*)d_in[3];
  const float* b1 = (const float*)d_in[4];
  const float* w2 = (const float*)d_in[5];
  const float* b2 = (const float*)d_in[6];
  const float* wi = (const float*)d_in[7];
  const float* wh = (const float*)d_in[8];
  const float* bi = (const float*)d_in[9];
  const float* bh = (const float*)d_in[10];
  const float* hw = (const float*)d_in[11];
  const float* hb = (const float*)d_in[12];

  float* out_x = (float*)d_out;                                  // [32,4096,4]
  float* out_z = out_x + (size_t)T_UNOBS_C * BATCH_C * 4;        // [32,4096,256]

  // workspace: weight splits only (~2.4 MB)
  unsigned short* p = (unsigned short*)d_ws;
  unsigned short* wi_hi = p; p += 768 * 256;
  unsigned short* wi_lo = p; p += 768 * 256;
  unsigned short* wh_hi = p; p += 768 * 256;
  unsigned short* wh_lo = p; p += 768 * 256;
  unsigned short* wc_hi = p; p += 768 * 256;
  unsigned short* wc_lo = p; p += 768 * 256;
  float* bc_obs = (float*)p;

  prep_kernel<<<768, 256, 0, stream>>>(wi, w2, b2, bi,
                                       wi_hi, wi_lo, wh, wh_hi, wh_lo,
                                       wc_hi, wc_lo, bc_obs);

  rnn_persistent<<<256, 512, 0, stream>>>(x_obs, t_obs, w1, b1,
                                          wi_hi, wi_lo, wh_hi, wh_lo,
                                          wc_hi, wc_lo, bc_obs, bi, bh,
                                          hw, hb, out_x, out_z);
}